// Round 8
// baseline (647.797 us; speedup 1.0000x reference)
//
#include <hip/hip_runtime.h>
#include <hip/hip_bf16.h>
#include <cstdint>

#define BB 8
#define CC 16
#define DD 32
#define HH 112
#define WW 112
#define TT 16        // D_OUT
#define HID 256
#define OUTN 128
#define INSZ 784     // C*7*7

__device__ __forceinline__ float bf16lo(uint32_t u) { return __uint_as_float(u << 16); }
__device__ __forceinline__ float bf16hi(uint32_t u) { return __uint_as_float(u & 0xffff0000u); }
__device__ __forceinline__ float bf16s(uint16_t u)  { return __uint_as_float(((uint32_t)u) << 16); }

__device__ __forceinline__ uint16_t f32_to_bf16_rne(float f) {
    uint32_t u = __float_as_uint(f);
    return (uint16_t)((u + 0x7fffu + ((u >> 16) & 1u)) >> 16);
}

// ---------------------------------------------------------------------------
// Dtype detector (PROVEN r2/r5/r6/r7): flag=1 -> float32, 0 -> bfloat16.
// ---------------------------------------------------------------------------
__global__ __launch_bounds__(256) void detect_kernel(const uint16_t* __restrict__ x,
                                                     int* __restrict__ flag) {
    __shared__ int cnt;
    if (threadIdx.x == 0) cnt = 0;
    __syncthreads();
    int local = 0;
    for (int i = threadIdx.x; i < 8192; i += 256) {
        uint32_t e = (x[i] >> 7) & 0xFFu;
        if (e == 0u || e >= 0x90u) local++;
    }
    atomicAdd(&cnt, local);
    __syncthreads();
    if (threadIdx.x == 0) *flag = (cnt > 400) ? 1 : 0;
}

// ---------------------------------------------------------------------------
// Pool (IDENTICAL to r5-r7 PASS): x -> seq (T,B,INSZ) f32, mean over 512.
// ---------------------------------------------------------------------------
__global__ __launch_bounds__(256) void pool_kernel(const void* __restrict__ xv,
                                                   float* __restrict__ seq,
                                                   const int* __restrict__ flag) {
    const int isf32 = *flag;
    int gid = blockIdx.x;                 // 2048 blocks
    int t = gid & 15, c = (gid >> 4) & 15, b = gid >> 8;
    long base = (long)(((b * CC + c) * DD) + t * 2) * (HH * WW);
    __shared__ float chunk[6272];
    int tid = threadIdx.x;
    float s = 0.0f;
    if (!isf32) {
        const uint4* p = reinterpret_cast<const uint4*>((const uint16_t*)xv + base);
        for (int m = tid; m < 3136; m += 256) {
            uint4 v = p[m];
            chunk[m] = bf16lo(v.x) + bf16hi(v.x) + bf16lo(v.y) + bf16hi(v.y)
                     + bf16lo(v.z) + bf16hi(v.z) + bf16lo(v.w) + bf16hi(v.w);
        }
        __syncthreads();
        if (tid < 49) {
            int h2 = tid / 7, w2 = tid - h2 * 7;
            #pragma unroll
            for (int d = 0; d < 2; d++)
                for (int hh = 0; hh < 16; hh++) {
                    int row = d * 1568 + (h2 * 16 + hh) * 14 + w2 * 2;
                    s += chunk[row] + chunk[row + 1];
                }
        }
    } else {
        const float4* p = reinterpret_cast<const float4*>((const float*)xv + base);
        for (int m = tid; m < 6272; m += 256) {
            float4 v = p[m];
            chunk[m] = v.x + v.y + v.z + v.w;
        }
        __syncthreads();
        if (tid < 49) {
            int h2 = tid / 7, w2 = tid - h2 * 7;
            #pragma unroll
            for (int d = 0; d < 2; d++)
                for (int hh = 0; hh < 16; hh++) {
                    int row = d * 3136 + (h2 * 16 + hh) * 28 + w2 * 4;
                    s += chunk[row] + chunk[row + 1] + chunk[row + 2] + chunk[row + 3];
                }
        }
    }
    if (tid < 49) {
        seq[(long)(t * BB + b) * INSZ + c * 49 + tid] = s * (1.0f / 512.0f);
    }
}

// ---------------------------------------------------------------------------
// W_ih -> f32 transposed wihT[k][768].
// ---------------------------------------------------------------------------
__global__ __launch_bounds__(256) void pack_wih(const void* __restrict__ W,
                                                float* __restrict__ WT,
                                                const int* __restrict__ flag) {
    const int isf32 = *flag;
    int g = blockIdx.x * 256 + threadIdx.x;   // 602112 exactly
    int j = g / INSZ, k = g - j * INSZ;
    float v = isf32 ? ((const float*)W)[g] : bf16s(((const uint16_t*)W)[g]);
    WT[(long)k * 768 + j] = v;
}

// ---------------------------------------------------------------------------
// W_hh -> packed bf16 uint4 quads, transposed: whhQ[kq][768], kq in [0,32).
// whhQ[kq*768 + j] holds W_hh[j][8kq .. 8kq+7] as 4 packed bf16-pairs.
// ---------------------------------------------------------------------------
__global__ __launch_bounds__(256) void pack_whh(const void* __restrict__ W,
                                                uint4* __restrict__ WQ,
                                                const int* __restrict__ flag) {
    const int isf32 = *flag;
    int g = blockIdx.x * 256 + threadIdx.x;   // 24576 exactly
    int j = g >> 5, kq = g & 31;
    uint4 u;
    if (isf32) {
        const float4* Wf4 = (const float4*)W;     // W[j][...] row-major
        float4 a = Wf4[j * 64 + 2 * kq];
        float4 b = Wf4[j * 64 + 2 * kq + 1];
        u.x = (uint32_t)f32_to_bf16_rne(a.x) | ((uint32_t)f32_to_bf16_rne(a.y) << 16);
        u.y = (uint32_t)f32_to_bf16_rne(a.z) | ((uint32_t)f32_to_bf16_rne(a.w) << 16);
        u.z = (uint32_t)f32_to_bf16_rne(b.x) | ((uint32_t)f32_to_bf16_rne(b.y) << 16);
        u.w = (uint32_t)f32_to_bf16_rne(b.z) | ((uint32_t)f32_to_bf16_rne(b.w) << 16);
    } else {
        u = ((const uint4*)W)[g];                 // 8 bf16 = one uint4, direct
    }
    WQ[kq * 768 + j] = u;
}

// ---------------------------------------------------------------------------
// gi (IDENTICAL to r6/r7 PASS): 96 blocks = 3 j-groups x 32 tb-groups of 4.
// ---------------------------------------------------------------------------
__global__ __launch_bounds__(256) void gi_kernel(const float* __restrict__ seq,
                                                 const float* __restrict__ wihT,
                                                 const void* __restrict__ bih,
                                                 float* __restrict__ gi,
                                                 const int* __restrict__ flag) {
    const int isf32 = *flag;
    int jg = blockIdx.x % 3, tbg = blockIdx.x / 3;
    int tb0 = tbg * 4;
    int j = jg * 256 + threadIdx.x;
    __shared__ __align__(16) float s_in[INSZ * 4];
    const float* sbase = seq + (long)tb0 * INSZ;
    for (int idx = threadIdx.x; idx < INSZ * 4; idx += 256) {
        int i = idx / INSZ, k = idx - i * INSZ;
        s_in[k * 4 + i] = sbase[idx];
    }
    __syncthreads();
    float bv = isf32 ? ((const float*)bih)[j] : bf16s(((const uint16_t*)bih)[j]);
    float a0 = bv, a1 = bv, a2 = bv, a3 = bv;
    const float* wp = wihT + j;
    const float4* s4 = reinterpret_cast<const float4*>(s_in);
    #pragma unroll 8
    for (int k = 0; k < INSZ; k++) {
        float w = wp[(long)k * 768];
        float4 sv = s4[k];
        a0 += w * sv.x; a1 += w * sv.y; a2 += w * sv.z; a3 += w * sv.w;
    }
    gi[(long)(tb0 + 0) * 768 + j] = a0;
    gi[(long)(tb0 + 1) * 768 + j] = a1;
    gi[(long)(tb0 + 2) * 768 + j] = a2;
    gi[(long)(tb0 + 3) * 768 + j] = a3;
}

// ---------------------------------------------------------------------------
// Sequential GRU. One block/batch, 768 threads. Thread j holds W_hh row j as
// 32 NAMED uint4 (128 VGPRs). amdgpu_waves_per_eu(3,3) pins the scheduler's
// occupancy target (r6/r7: launch_bounds min-only -> scheduler chased 6/EU,
// remat'd the loads, VGPR=84, 163-196us). If remat still fires, the fallback
// is 32 coalesced dwordx4 streams/step (good MLP) instead of 128 scalars.
// ---------------------------------------------------------------------------
#define F32Q(X) \
  X(0)X(1)X(2)X(3)X(4)X(5)X(6)X(7)X(8)X(9)X(10)X(11)X(12)X(13)X(14)X(15) \
  X(16)X(17)X(18)X(19)X(20)X(21)X(22)X(23)X(24)X(25)X(26)X(27)X(28)X(29)X(30)X(31)

__global__ __launch_bounds__(768)
__attribute__((amdgpu_waves_per_eu(3, 3)))
void gru_kernel(const float* __restrict__ gi,
                const uint4* __restrict__ whhQ,
                const void* __restrict__ bhh,
                const void* __restrict__ Wout,
                const void* __restrict__ bout,
                void* __restrict__ out,
                const int* __restrict__ flag) {
    const int isf32 = *flag;
    int b = blockIdx.x;
    int j = threadIdx.x;
    __shared__ __align__(16) float h_s[HID];
    __shared__ __align__(16) float g_s[768];
    if (j < HID) h_s[j] = 0.0f;
    float bh = isf32 ? ((const float*)bhh)[j] : bf16s(((const uint16_t*)bhh)[j]);

    const uint4* wq = whhQ + j;
#define QLOAD(i) const uint4 q##i = wq[i * 768];
    F32Q(QLOAD)
#undef QLOAD

    __syncthreads();
    #pragma unroll 1
    for (int t = 0; t < TT; t++) {
        float a0 = bh, a1 = 0.0f, a2 = 0.0f, a3 = 0.0f;
        const float4* h4p = reinterpret_cast<const float4*>(h_s);
        // q##i covers k in [8i, 8i+8) -> h4p[2i], h4p[2i+1]
#define QDOT(i) { float4 ha = h4p[2*i], hb = h4p[2*i+1];                          \
        a0 += bf16lo(q##i.x) * ha.x + bf16hi(q##i.x) * ha.y;                      \
        a1 += bf16lo(q##i.y) * ha.z + bf16hi(q##i.y) * ha.w;                      \
        a2 += bf16lo(q##i.z) * hb.x + bf16hi(q##i.z) * hb.y;                      \
        a3 += bf16lo(q##i.w) * hb.z + bf16hi(q##i.w) * hb.w; }
        F32Q(QDOT)
#undef QDOT
        g_s[j] = (a0 + a1) + (a2 + a3);
        __syncthreads();                             // g ready; dots done with h_s
        if (j < HID) {
            const float* gp = gi + (long)(t * BB + b) * 768;
            float r = 1.0f / (1.0f + __expf(-(gp[j]       + g_s[j])));
            float z = 1.0f / (1.0f + __expf(-(gp[j + 256] + g_s[j + 256])));
            float npre = gp[j + 512] + r * g_s[j + 512];
            float n = 2.0f / (1.0f + __expf(-2.0f * npre)) - 1.0f;  // tanh
            h_s[j] = (1.0f - z) * n + z * h_s[j];
        }
        __syncthreads();                             // h ready for next step
    }
    if (j < OUTN) {
        float acc = isf32 ? ((const float*)bout)[j] : bf16s(((const uint16_t*)bout)[j]);
        if (!isf32) {
            const uint4* wo = reinterpret_cast<const uint4*>((const uint16_t*)Wout + (long)j * HID);
            #pragma unroll
            for (int k = 0; k < 32; k++) {
                uint4 v = wo[k];
                const float* hp2 = &h_s[k * 8];
                acc += bf16lo(v.x) * hp2[0] + bf16hi(v.x) * hp2[1]
                     + bf16lo(v.y) * hp2[2] + bf16hi(v.y) * hp2[3]
                     + bf16lo(v.z) * hp2[4] + bf16hi(v.z) * hp2[5]
                     + bf16lo(v.w) * hp2[6] + bf16hi(v.w) * hp2[7];
            }
            ((uint16_t*)out)[b * OUTN + j] = f32_to_bf16_rne(acc);
        } else {
            const float4* wo = reinterpret_cast<const float4*>((const float*)Wout + (long)j * HID);
            #pragma unroll
            for (int k = 0; k < 64; k++) {
                float4 v = wo[k];
                const float* hp2 = &h_s[k * 4];
                acc += v.x * hp2[0] + v.y * hp2[1] + v.z * hp2[2] + v.w * hp2[3];
            }
            ((float*)out)[b * OUTN + j] = acc;
        }
    }
}

extern "C" void kernel_launch(void* const* d_in, const int* in_sizes, int n_in,
                              void* d_out, int out_size, void* d_ws, size_t ws_size,
                              hipStream_t stream) {
    const void* x    = d_in[0];  // 8*16*32*112*112
    const void* Wih  = d_in[1];  // 768*784
    const void* Whh  = d_in[2];  // 768*256
    const void* bih  = d_in[3];  // 768
    const void* bhh  = d_in[4];  // 768
    const void* Wout = d_in[5];  // 128*256
    const void* bout = d_in[6];  // 128

    char* ws = (char*)d_ws;
    float* seq  = (float*)ws;                  // 401408 B
    float* gi   = (float*)(ws + 401408);       // 393216 B
    float* wihT = (float*)(ws + 1048576);      // 2408448 B  [784][768] f32
    uint4* whhQ = (uint4*)(ws + 4194304);      // 393216 B   [32][768] uint4
    int*  flagp = (int*)(ws + 8388608);

    detect_kernel<<<1, 256, 0, stream>>>((const uint16_t*)x, flagp);
    pool_kernel<<<2048, 256, 0, stream>>>(x, seq, flagp);
    pack_wih<<<2352, 256, 0, stream>>>(Wih, wihT, flagp);
    pack_whh<<<96, 256, 0, stream>>>(Whh, whhQ, flagp);
    gi_kernel<<<96, 256, 0, stream>>>(seq, wihT, bih, gi, flagp);
    gru_kernel<<<8, 768, 0, stream>>>(gi, whhQ, bhh, Wout, bout, d_out, flagp);
}

// Round 9
// 646.260 us; speedup vs baseline: 1.0024x; 1.0024x over previous
//
#include <hip/hip_runtime.h>
#include <hip/hip_bf16.h>
#include <cstdint>

#define BB 8
#define CC 16
#define DD 32
#define HH 112
#define WW 112
#define TT 16        // D_OUT
#define HID 256
#define OUTN 128
#define INSZ 784     // C*7*7

__device__ __forceinline__ float bf16lo(uint32_t u) { return __uint_as_float(u << 16); }
__device__ __forceinline__ float bf16hi(uint32_t u) { return __uint_as_float(u & 0xffff0000u); }
__device__ __forceinline__ float bf16s(uint16_t u)  { return __uint_as_float(((uint32_t)u) << 16); }

__device__ __forceinline__ uint16_t f32_to_bf16_rne(float f) {
    uint32_t u = __float_as_uint(f);
    return (uint16_t)((u + 0x7fffu + ((u >> 16) & 1u)) >> 16);
}

// ---------------------------------------------------------------------------
// Dtype detector (PROVEN r2/r5-r8): flag=1 -> float32, 0 -> bfloat16.
// ---------------------------------------------------------------------------
__global__ __launch_bounds__(256) void detect_kernel(const uint16_t* __restrict__ x,
                                                     int* __restrict__ flag) {
    __shared__ int cnt;
    if (threadIdx.x == 0) cnt = 0;
    __syncthreads();
    int local = 0;
    for (int i = threadIdx.x; i < 8192; i += 256) {
        uint32_t e = (x[i] >> 7) & 0xFFu;
        if (e == 0u || e >= 0x90u) local++;
    }
    atomicAdd(&cnt, local);
    __syncthreads();
    if (threadIdx.x == 0) *flag = (cnt > 400) ? 1 : 0;
}

// ---------------------------------------------------------------------------
// Pool (IDENTICAL to r5-r8 PASS): x -> seq (T,B,INSZ) f32, mean over 512.
// ---------------------------------------------------------------------------
__global__ __launch_bounds__(256) void pool_kernel(const void* __restrict__ xv,
                                                   float* __restrict__ seq,
                                                   const int* __restrict__ flag) {
    const int isf32 = *flag;
    int gid = blockIdx.x;                 // 2048 blocks
    int t = gid & 15, c = (gid >> 4) & 15, b = gid >> 8;
    long base = (long)(((b * CC + c) * DD) + t * 2) * (HH * WW);
    __shared__ float chunk[6272];
    int tid = threadIdx.x;
    float s = 0.0f;
    if (!isf32) {
        const uint4* p = reinterpret_cast<const uint4*>((const uint16_t*)xv + base);
        for (int m = tid; m < 3136; m += 256) {
            uint4 v = p[m];
            chunk[m] = bf16lo(v.x) + bf16hi(v.x) + bf16lo(v.y) + bf16hi(v.y)
                     + bf16lo(v.z) + bf16hi(v.z) + bf16lo(v.w) + bf16hi(v.w);
        }
        __syncthreads();
        if (tid < 49) {
            int h2 = tid / 7, w2 = tid - h2 * 7;
            #pragma unroll
            for (int d = 0; d < 2; d++)
                for (int hh = 0; hh < 16; hh++) {
                    int row = d * 1568 + (h2 * 16 + hh) * 14 + w2 * 2;
                    s += chunk[row] + chunk[row + 1];
                }
        }
    } else {
        const float4* p = reinterpret_cast<const float4*>((const float*)xv + base);
        for (int m = tid; m < 6272; m += 256) {
            float4 v = p[m];
            chunk[m] = v.x + v.y + v.z + v.w;
        }
        __syncthreads();
        if (tid < 49) {
            int h2 = tid / 7, w2 = tid - h2 * 7;
            #pragma unroll
            for (int d = 0; d < 2; d++)
                for (int hh = 0; hh < 16; hh++) {
                    int row = d * 3136 + (h2 * 16 + hh) * 28 + w2 * 4;
                    s += chunk[row] + chunk[row + 1] + chunk[row + 2] + chunk[row + 3];
                }
        }
    }
    if (tid < 49) {
        seq[(long)(t * BB + b) * INSZ + c * 49 + tid] = s * (1.0f / 512.0f);
    }
}

// ---------------------------------------------------------------------------
// W_ih -> f32 transposed wihT[k][768].
// ---------------------------------------------------------------------------
__global__ __launch_bounds__(256) void pack_wih(const void* __restrict__ W,
                                                float* __restrict__ WT,
                                                const int* __restrict__ flag) {
    const int isf32 = *flag;
    int g = blockIdx.x * 256 + threadIdx.x;   // 602112 exactly
    int j = g / INSZ, k = g - j * INSZ;
    float v = isf32 ? ((const float*)W)[g] : bf16s(((const uint16_t*)W)[g]);
    WT[(long)k * 768 + j] = v;
}

// ---------------------------------------------------------------------------
// W_hh -> packed bf16 uint4 quads, transposed: whhQ[kq][768], kq in [0,32).
// whhQ[kq*768 + j] holds W_hh[j][8kq .. 8kq+7] as 4 packed bf16-pairs.
// ---------------------------------------------------------------------------
__global__ __launch_bounds__(256) void pack_whh(const void* __restrict__ W,
                                                uint4* __restrict__ WQ,
                                                const int* __restrict__ flag) {
    const int isf32 = *flag;
    int g = blockIdx.x * 256 + threadIdx.x;   // 24576 exactly
    int j = g >> 5, kq = g & 31;
    uint4 u;
    if (isf32) {
        const float4* Wf4 = (const float4*)W;     // W[j][...] row-major
        float4 a = Wf4[j * 64 + 2 * kq];
        float4 b = Wf4[j * 64 + 2 * kq + 1];
        u.x = (uint32_t)f32_to_bf16_rne(a.x) | ((uint32_t)f32_to_bf16_rne(a.y) << 16);
        u.y = (uint32_t)f32_to_bf16_rne(a.z) | ((uint32_t)f32_to_bf16_rne(a.w) << 16);
        u.z = (uint32_t)f32_to_bf16_rne(b.x) | ((uint32_t)f32_to_bf16_rne(b.y) << 16);
        u.w = (uint32_t)f32_to_bf16_rne(b.z) | ((uint32_t)f32_to_bf16_rne(b.w) << 16);
    } else {
        u = ((const uint4*)W)[g];                 // 8 bf16 = one uint4, direct
    }
    WQ[kq * 768 + j] = u;
}

// ---------------------------------------------------------------------------
// gi (IDENTICAL to r6-r8 PASS): 96 blocks = 3 j-groups x 32 tb-groups of 4.
// ---------------------------------------------------------------------------
__global__ __launch_bounds__(256) void gi_kernel(const float* __restrict__ seq,
                                                 const float* __restrict__ wihT,
                                                 const void* __restrict__ bih,
                                                 float* __restrict__ gi,
                                                 const int* __restrict__ flag) {
    const int isf32 = *flag;
    int jg = blockIdx.x % 3, tbg = blockIdx.x / 3;
    int tb0 = tbg * 4;
    int j = jg * 256 + threadIdx.x;
    __shared__ __align__(16) float s_in[INSZ * 4];
    const float* sbase = seq + (long)tb0 * INSZ;
    for (int idx = threadIdx.x; idx < INSZ * 4; idx += 256) {
        int i = idx / INSZ, k = idx - i * INSZ;
        s_in[k * 4 + i] = sbase[idx];
    }
    __syncthreads();
    float bv = isf32 ? ((const float*)bih)[j] : bf16s(((const uint16_t*)bih)[j]);
    float a0 = bv, a1 = bv, a2 = bv, a3 = bv;
    const float* wp = wihT + j;
    const float4* s4 = reinterpret_cast<const float4*>(s_in);
    #pragma unroll 8
    for (int k = 0; k < INSZ; k++) {
        float w = wp[(long)k * 768];
        float4 sv = s4[k];
        a0 += w * sv.x; a1 += w * sv.y; a2 += w * sv.z; a3 += w * sv.w;
    }
    gi[(long)(tb0 + 0) * 768 + j] = a0;
    gi[(long)(tb0 + 1) * 768 + j] = a1;
    gi[(long)(tb0 + 2) * 768 + j] = a2;
    gi[(long)(tb0 + 3) * 768 + j] = a3;
}

// ---------------------------------------------------------------------------
// Sequential GRU. One block/batch, 768 threads. Thread j holds W_hh row j,
// k=0..191, as 24 uint4 (96 VGPRs) PINNED via empty asm (defeats the
// MachineSink pass that re-streamed the loads in r6/r7/r8 -> VGPR stuck at
// 84, 163-298us). k=192..255 is streamed in-loop (8 coalesced uint4/thread,
// 98KB/step, hidden under compute). waves_per_eu(3,3) grants 168-VGPR budget.
// ---------------------------------------------------------------------------
#define F24Q(X) \
  X(0)X(1)X(2)X(3)X(4)X(5)X(6)X(7)X(8)X(9)X(10)X(11) \
  X(12)X(13)X(14)X(15)X(16)X(17)X(18)X(19)X(20)X(21)X(22)X(23)
#define F8S(X) X(24)X(25)X(26)X(27)X(28)X(29)X(30)X(31)

__global__ __launch_bounds__(768)
__attribute__((amdgpu_waves_per_eu(3, 3)))
void gru_kernel(const float* __restrict__ gi,
                const uint4* __restrict__ whhQ,
                const void* __restrict__ bhh,
                const void* __restrict__ Wout,
                const void* __restrict__ bout,
                void* __restrict__ out,
                const int* __restrict__ flag) {
    const int isf32 = *flag;
    int b = blockIdx.x;
    int j = threadIdx.x;
    __shared__ __align__(16) float h_s[HID];
    __shared__ __align__(16) float g_s[768];
    if (j < HID) h_s[j] = 0.0f;
    float bh = isf32 ? ((const float*)bhh)[j] : bf16s(((const uint16_t*)bhh)[j]);

    const uint4* wq = whhQ + j;
    // Pinned weights k=0..191: load once, then opaque-pin so they cannot be
    // sunk into the loop or rematerialized — only kept (or RA-spilled).
#define QLOAD(i) uint4 q##i = wq[i * 768]; \
    asm volatile("" : "+v"(q##i.x), "+v"(q##i.y), "+v"(q##i.z), "+v"(q##i.w));
    F24Q(QLOAD)
#undef QLOAD

    __syncthreads();
    #pragma unroll 1
    for (int t = 0; t < TT; t++) {
        float a0 = bh, a1 = 0.0f, a2 = 0.0f, a3 = 0.0f;
        const float4* h4p = reinterpret_cast<const float4*>(h_s);
        // q##i covers k in [8i, 8i+8) -> h4p[2i], h4p[2i+1]
#define QDOT(i) { float4 ha = h4p[2*i], hb = h4p[2*i+1];                          \
        a0 += bf16lo(q##i.x) * ha.x + bf16hi(q##i.x) * ha.y;                      \
        a1 += bf16lo(q##i.y) * ha.z + bf16hi(q##i.y) * ha.w;                      \
        a2 += bf16lo(q##i.z) * hb.x + bf16hi(q##i.z) * hb.y;                      \
        a3 += bf16lo(q##i.w) * hb.z + bf16hi(q##i.w) * hb.w; }
        F24Q(QDOT)
        // Streamed tail k=192..255: coalesced uint4 loads each step.
#define QSTREAM(i) { uint4 qs = wq[i * 768]; float4 ha = h4p[2*i], hb = h4p[2*i+1]; \
        a0 += bf16lo(qs.x) * ha.x + bf16hi(qs.x) * ha.y;                           \
        a1 += bf16lo(qs.y) * ha.z + bf16hi(qs.y) * ha.w;                           \
        a2 += bf16lo(qs.z) * hb.x + bf16hi(qs.z) * hb.y;                           \
        a3 += bf16lo(qs.w) * hb.z + bf16hi(qs.w) * hb.w; }
        F8S(QSTREAM)
#undef QSTREAM
#undef QDOT
        g_s[j] = (a0 + a1) + (a2 + a3);
        __syncthreads();                             // g ready; dots done with h_s
        if (j < HID) {
            const float* gp = gi + (long)(t * BB + b) * 768;
            float r = 1.0f / (1.0f + __expf(-(gp[j]       + g_s[j])));
            float z = 1.0f / (1.0f + __expf(-(gp[j + 256] + g_s[j + 256])));
            float npre = gp[j + 512] + r * g_s[j + 512];
            float n = 2.0f / (1.0f + __expf(-2.0f * npre)) - 1.0f;  // tanh
            h_s[j] = (1.0f - z) * n + z * h_s[j];
        }
        __syncthreads();                             // h ready for next step
    }
    if (j < OUTN) {
        float acc = isf32 ? ((const float*)bout)[j] : bf16s(((const uint16_t*)bout)[j]);
        if (!isf32) {
            const uint4* wo = reinterpret_cast<const uint4*>((const uint16_t*)Wout + (long)j * HID);
            #pragma unroll
            for (int k = 0; k < 32; k++) {
                uint4 v = wo[k];
                const float* hp2 = &h_s[k * 8];
                acc += bf16lo(v.x) * hp2[0] + bf16hi(v.x) * hp2[1]
                     + bf16lo(v.y) * hp2[2] + bf16hi(v.y) * hp2[3]
                     + bf16lo(v.z) * hp2[4] + bf16hi(v.z) * hp2[5]
                     + bf16lo(v.w) * hp2[6] + bf16hi(v.w) * hp2[7];
            }
            ((uint16_t*)out)[b * OUTN + j] = f32_to_bf16_rne(acc);
        } else {
            const float4* wo = reinterpret_cast<const float4*>((const float*)Wout + (long)j * HID);
            #pragma unroll
            for (int k = 0; k < 64; k++) {
                float4 v = wo[k];
                const float* hp2 = &h_s[k * 4];
                acc += v.x * hp2[0] + v.y * hp2[1] + v.z * hp2[2] + v.w * hp2[3];
            }
            ((float*)out)[b * OUTN + j] = acc;
        }
    }
}

extern "C" void kernel_launch(void* const* d_in, const int* in_sizes, int n_in,
                              void* d_out, int out_size, void* d_ws, size_t ws_size,
                              hipStream_t stream) {
    const void* x    = d_in[0];  // 8*16*32*112*112
    const void* Wih  = d_in[1];  // 768*784
    const void* Whh  = d_in[2];  // 768*256
    const void* bih  = d_in[3];  // 768
    const void* bhh  = d_in[4];  // 768
    const void* Wout = d_in[5];  // 128*256
    const void* bout = d_in[6];  // 128

    char* ws = (char*)d_ws;
    float* seq  = (float*)ws;                  // 401408 B
    float* gi   = (float*)(ws + 401408);       // 393216 B
    float* wihT = (float*)(ws + 1048576);      // 2408448 B  [784][768] f32
    uint4* whhQ = (uint4*)(ws + 4194304);      // 393216 B   [32][768] uint4
    int*  flagp = (int*)(ws + 8388608);

    detect_kernel<<<1, 256, 0, stream>>>((const uint16_t*)x, flagp);
    pool_kernel<<<2048, 256, 0, stream>>>(x, seq, flagp);
    pack_wih<<<2352, 256, 0, stream>>>(Wih, wihT, flagp);
    pack_whh<<<96, 256, 0, stream>>>(Whh, whhQ, flagp);
    gi_kernel<<<96, 256, 0, stream>>>(seq, wihT, bih, gi, flagp);
    gru_kernel<<<8, 768, 0, stream>>>(gi, whhQ, bhh, Wout, bout, d_out, flagp);
}

// Round 10
// 437.102 us; speedup vs baseline: 1.4820x; 1.4785x over previous
//
#include <hip/hip_runtime.h>
#include <hip/hip_bf16.h>
#include <cstdint>

#define BB 8
#define CC 16
#define DD 32
#define HH 112
#define WW 112
#define TT 16        // D_OUT
#define HID 256
#define OUTN 128
#define INSZ 784     // C*7*7

__device__ __forceinline__ float bf16lo(uint32_t u) { return __uint_as_float(u << 16); }
__device__ __forceinline__ float bf16hi(uint32_t u) { return __uint_as_float(u & 0xffff0000u); }
__device__ __forceinline__ float bf16s(uint16_t u)  { return __uint_as_float(((uint32_t)u) << 16); }

__device__ __forceinline__ uint16_t f32_to_bf16_rne(float f) {
    uint32_t u = __float_as_uint(f);
    return (uint16_t)((u + 0x7fffu + ((u >> 16) & 1u)) >> 16);
}

// ---------------------------------------------------------------------------
// Dtype detector (PROVEN r2/r5-r9): flag=1 -> float32, 0 -> bfloat16.
// ---------------------------------------------------------------------------
__global__ __launch_bounds__(256) void detect_kernel(const uint16_t* __restrict__ x,
                                                     int* __restrict__ flag) {
    __shared__ int cnt;
    if (threadIdx.x == 0) cnt = 0;
    __syncthreads();
    int local = 0;
    for (int i = threadIdx.x; i < 8192; i += 256) {
        uint32_t e = (x[i] >> 7) & 0xFFu;
        if (e == 0u || e >= 0x90u) local++;
    }
    atomicAdd(&cnt, local);
    __syncthreads();
    if (threadIdx.x == 0) *flag = (cnt > 400) ? 1 : 0;
}

// ---------------------------------------------------------------------------
// Pool (IDENTICAL to r5-r9 PASS): x -> seq (T,B,INSZ) f32, mean over 512.
// ---------------------------------------------------------------------------
__global__ __launch_bounds__(256) void pool_kernel(const void* __restrict__ xv,
                                                   float* __restrict__ seq,
                                                   const int* __restrict__ flag) {
    const int isf32 = *flag;
    int gid = blockIdx.x;                 // 2048 blocks
    int t = gid & 15, c = (gid >> 4) & 15, b = gid >> 8;
    long base = (long)(((b * CC + c) * DD) + t * 2) * (HH * WW);
    __shared__ float chunk[6272];
    int tid = threadIdx.x;
    float s = 0.0f;
    if (!isf32) {
        const uint4* p = reinterpret_cast<const uint4*>((const uint16_t*)xv + base);
        for (int m = tid; m < 3136; m += 256) {
            uint4 v = p[m];
            chunk[m] = bf16lo(v.x) + bf16hi(v.x) + bf16lo(v.y) + bf16hi(v.y)
                     + bf16lo(v.z) + bf16hi(v.z) + bf16lo(v.w) + bf16hi(v.w);
        }
        __syncthreads();
        if (tid < 49) {
            int h2 = tid / 7, w2 = tid - h2 * 7;
            #pragma unroll
            for (int d = 0; d < 2; d++)
                for (int hh = 0; hh < 16; hh++) {
                    int row = d * 1568 + (h2 * 16 + hh) * 14 + w2 * 2;
                    s += chunk[row] + chunk[row + 1];
                }
        }
    } else {
        const float4* p = reinterpret_cast<const float4*>((const float*)xv + base);
        for (int m = tid; m < 6272; m += 256) {
            float4 v = p[m];
            chunk[m] = v.x + v.y + v.z + v.w;
        }
        __syncthreads();
        if (tid < 49) {
            int h2 = tid / 7, w2 = tid - h2 * 7;
            #pragma unroll
            for (int d = 0; d < 2; d++)
                for (int hh = 0; hh < 16; hh++) {
                    int row = d * 3136 + (h2 * 16 + hh) * 28 + w2 * 4;
                    s += chunk[row] + chunk[row + 1] + chunk[row + 2] + chunk[row + 3];
                }
        }
    }
    if (tid < 49) {
        seq[(long)(t * BB + b) * INSZ + c * 49 + tid] = s * (1.0f / 512.0f);
    }
}

// ---------------------------------------------------------------------------
// W_ih -> f32 transposed wihT[k][768].
// ---------------------------------------------------------------------------
__global__ __launch_bounds__(256) void pack_wih(const void* __restrict__ W,
                                                float* __restrict__ WT,
                                                const int* __restrict__ flag) {
    const int isf32 = *flag;
    int g = blockIdx.x * 256 + threadIdx.x;   // 602112 exactly
    int j = g / INSZ, k = g - j * INSZ;
    float v = isf32 ? ((const float*)W)[g] : bf16s(((const uint16_t*)W)[g]);
    WT[(long)k * 768 + j] = v;
}

// ---------------------------------------------------------------------------
// W_hh -> packed bf16 pairs, transposed: whhP[kk][768], kk in [0,128).
// whhP[kk*768 + j] = (W_hh[j][2kk], W_hh[j][2kk+1]) packed lo|hi.
// (r6-proven numerics: absmax 4.9e-4 with f32->bf16 quantization.)
// ---------------------------------------------------------------------------
__global__ __launch_bounds__(256) void pack_whh(const void* __restrict__ W,
                                                uint32_t* __restrict__ WP,
                                                const int* __restrict__ flag) {
    const int isf32 = *flag;
    int g = blockIdx.x * 256 + threadIdx.x;   // 98304 exactly
    int j = g >> 7, kk = g & 127;
    uint32_t u;
    if (isf32) {
        float2 v = ((const float2*)W)[g];     // W[j][2kk], W[j][2kk+1]
        u = (uint32_t)f32_to_bf16_rne(v.x) | ((uint32_t)f32_to_bf16_rne(v.y) << 16);
    } else {
        u = ((const uint32_t*)W)[g];
    }
    WP[kk * 768 + j] = u;
}

// ---------------------------------------------------------------------------
// gi (IDENTICAL to r6-r9 PASS): 96 blocks = 3 j-groups x 32 tb-groups of 4.
// ---------------------------------------------------------------------------
__global__ __launch_bounds__(256) void gi_kernel(const float* __restrict__ seq,
                                                 const float* __restrict__ wihT,
                                                 const void* __restrict__ bih,
                                                 float* __restrict__ gi,
                                                 const int* __restrict__ flag) {
    const int isf32 = *flag;
    int jg = blockIdx.x % 3, tbg = blockIdx.x / 3;
    int tb0 = tbg * 4;
    int j = jg * 256 + threadIdx.x;
    __shared__ __align__(16) float s_in[INSZ * 4];
    const float* sbase = seq + (long)tb0 * INSZ;
    for (int idx = threadIdx.x; idx < INSZ * 4; idx += 256) {
        int i = idx / INSZ, k = idx - i * INSZ;
        s_in[k * 4 + i] = sbase[idx];
    }
    __syncthreads();
    float bv = isf32 ? ((const float*)bih)[j] : bf16s(((const uint16_t*)bih)[j]);
    float a0 = bv, a1 = bv, a2 = bv, a3 = bv;
    const float* wp = wihT + j;
    const float4* s4 = reinterpret_cast<const float4*>(s_in);
    #pragma unroll 8
    for (int k = 0; k < INSZ; k++) {
        float w = wp[(long)k * 768];
        float4 sv = s4[k];
        a0 += w * sv.x; a1 += w * sv.y; a2 += w * sv.z; a3 += w * sv.w;
    }
    gi[(long)(tb0 + 0) * 768 + j] = a0;
    gi[(long)(tb0 + 1) * 768 + j] = a1;
    gi[(long)(tb0 + 2) * 768 + j] = a2;
    gi[(long)(tb0 + 3) * 768 + j] = a3;
}

// ---------------------------------------------------------------------------
// Sequential GRU — r5's PROVEN structure (simple rolled coalesced stream,
// the fastest measured gru form: ~6us/step at f32), with bytes halved via
// packed-bf16 pairs. NO register-residency tricks (r6-r9 all failed at
// VGPR=84; r5's compiler-pipelined rolled loop is the winner).
// One block/batch, 768 threads; thread j streams W_hh row j each step.
// ---------------------------------------------------------------------------
__global__ __launch_bounds__(768) void gru_kernel(const float* __restrict__ gi,
                                                  const uint32_t* __restrict__ whhP,
                                                  const void* __restrict__ bhh,
                                                  const void* __restrict__ Wout,
                                                  const void* __restrict__ bout,
                                                  void* __restrict__ out,
                                                  const int* __restrict__ flag) {
    const int isf32 = *flag;
    int b = blockIdx.x;
    int j = threadIdx.x;
    __shared__ __align__(16) float h_s[HID];
    __shared__ __align__(16) float g_s[768];
    if (j < HID) h_s[j] = 0.0f;
    float bh = isf32 ? ((const float*)bhh)[j] : bf16s(((const uint16_t*)bhh)[j]);
    const uint32_t* wp = whhP + j;
    __syncthreads();
    #pragma unroll 1
    for (int t = 0; t < TT; t++) {
        float a0 = bh, a1 = 0.0f;
        const float2* h2p = reinterpret_cast<const float2*>(h_s);
        #pragma unroll 8
        for (int kk = 0; kk < 128; kk++) {
            uint32_t u = wp[kk * 768];           // coalesced u32 stream
            float2 hv = h2p[kk];                 // LDS broadcast
            a0 += bf16lo(u) * hv.x;
            a1 += bf16hi(u) * hv.y;
        }
        g_s[j] = a0 + a1;
        __syncthreads();                         // g ready; dots done with h_s
        if (j < HID) {
            const float* gp = gi + (long)(t * BB + b) * 768;
            float r = 1.0f / (1.0f + __expf(-(gp[j]       + g_s[j])));
            float z = 1.0f / (1.0f + __expf(-(gp[j + 256] + g_s[j + 256])));
            float npre = gp[j + 512] + r * g_s[j + 512];
            float n = 2.0f / (1.0f + __expf(-2.0f * npre)) - 1.0f;  // tanh
            h_s[j] = (1.0f - z) * n + z * h_s[j];
        }
        __syncthreads();                         // h ready for next step
    }
    if (j < OUTN) {
        float acc = isf32 ? ((const float*)bout)[j] : bf16s(((const uint16_t*)bout)[j]);
        if (!isf32) {
            const uint4* wo = reinterpret_cast<const uint4*>((const uint16_t*)Wout + (long)j * HID);
            #pragma unroll
            for (int k = 0; k < 32; k++) {
                uint4 v = wo[k];
                const float* hp2 = &h_s[k * 8];
                acc += bf16lo(v.x) * hp2[0] + bf16hi(v.x) * hp2[1]
                     + bf16lo(v.y) * hp2[2] + bf16hi(v.y) * hp2[3]
                     + bf16lo(v.z) * hp2[4] + bf16hi(v.z) * hp2[5]
                     + bf16lo(v.w) * hp2[6] + bf16hi(v.w) * hp2[7];
            }
            ((uint16_t*)out)[b * OUTN + j] = f32_to_bf16_rne(acc);
        } else {
            const float4* wo = reinterpret_cast<const float4*>((const float*)Wout + (long)j * HID);
            #pragma unroll
            for (int k = 0; k < 64; k++) {
                float4 v = wo[k];
                const float* hp2 = &h_s[k * 4];
                acc += v.x * hp2[0] + v.y * hp2[1] + v.z * hp2[2] + v.w * hp2[3];
            }
            ((float*)out)[b * OUTN + j] = acc;
        }
    }
}

extern "C" void kernel_launch(void* const* d_in, const int* in_sizes, int n_in,
                              void* d_out, int out_size, void* d_ws, size_t ws_size,
                              hipStream_t stream) {
    const void* x    = d_in[0];  // 8*16*32*112*112
    const void* Wih  = d_in[1];  // 768*784
    const void* Whh  = d_in[2];  // 768*256
    const void* bih  = d_in[3];  // 768
    const void* bhh  = d_in[4];  // 768
    const void* Wout = d_in[5];  // 128*256
    const void* bout = d_in[6];  // 128

    char* ws = (char*)d_ws;
    float*    seq  = (float*)ws;                  // 401408 B
    float*    gi   = (float*)(ws + 401408);       // 393216 B
    float*    wihT = (float*)(ws + 1048576);      // 2408448 B  [784][768] f32
    uint32_t* whhP = (uint32_t*)(ws + 4194304);   // 393216 B   [128][768] u32
    int*     flagp = (int*)(ws + 8388608);

    detect_kernel<<<1, 256, 0, stream>>>((const uint16_t*)x, flagp);
    pool_kernel<<<2048, 256, 0, stream>>>(x, seq, flagp);
    pack_wih<<<2352, 256, 0, stream>>>(Wih, wihT, flagp);
    pack_whh<<<384, 256, 0, stream>>>(Whh, whhP, flagp);
    gi_kernel<<<96, 256, 0, stream>>>(seq, wihT, bih, gi, flagp);
    gru_kernel<<<8, 768, 0, stream>>>(gi, whhP, bhh, Wout, bout, d_out, flagp);
}